// Round 10
// baseline (211.670 us; speedup 1.0000x reference)
//
#include <hip/hip_runtime.h>

// v4 = v3 (unchanged, produces correct output) + two read-only BW probes for
// diagnosis. Three structurally different scan kernels all hit ~65us/2TB/s;
// probes split "environment ceiling" vs "kernel structure" hypotheses.

constexpr int T_LEN   = 8192;
constexpr int THREADS = 256;
constexpr int SEGS    = 4;
constexpr int SEG_LEN = T_LEN / SEGS;       // 2048
constexpr int PER     = SEG_LEN / THREADS;  // 8 elems/thread/segment
constexpr float E_INF_C = 0.5f;
constexpr float E_C     = 2.0f;
constexpr float K_C     = 2.0f;             // E/ETA

__global__ __launch_bounds__(THREADS) void maxwell_seg_kernel(
    const float* __restrict__ eps, const float* __restrict__ dts,
    float* __restrict__ out)
{
    const int row  = blockIdx.x;
    const int tid  = threadIdx.x;
    const int lane = tid & 63;
    const int wave = tid >> 6;

    __shared__ float wA[4], wB[4];
    __shared__ float sA[THREADS], sB[THREADS];

    const long long rbase = (long long)row * T_LEN;

    float4 ev[2], dv[2], evn[2], dvn[2];

    {
        const float4* p = reinterpret_cast<const float4*>(eps + rbase + tid * PER);
        const float4* q = reinterpret_cast<const float4*>(dts + rbase + tid * PER);
        ev[0] = p[0]; ev[1] = p[1];
        dv[0] = q[0]; dv[1] = q[1];
    }

    float carry = 0.f;

#pragma unroll
    for (int s = 0; s < SEGS; ++s) {
        if (s + 1 < SEGS) {
            const long long nb = rbase + (long long)(s + 1) * SEG_LEN + tid * PER;
            const float4* p = reinterpret_cast<const float4*>(eps + nb);
            const float4* q = reinterpret_cast<const float4*>(dts + nb);
            evn[0] = p[0]; evn[1] = p[1];
            dvn[0] = q[0]; dvn[1] = q[1];
        }

        float a = 1.f, b = 0.f;
#pragma unroll
        for (int j = 0; j < 2; ++j) {
            const float4 e = ev[j], d = dv[j];
            float an, t;
            t = K_C * d.x; an = 1.f - t; b = an * b + t * e.x; a = an * a;
            t = K_C * d.y; an = 1.f - t; b = an * b + t * e.y; a = an * a;
            t = K_C * d.z; an = 1.f - t; b = an * b + t * e.z; a = an * a;
            t = K_C * d.w; an = 1.f - t; b = an * b + t * e.w; a = an * a;
        }

        float A = a, B = b;
#pragma unroll
        for (int off = 1; off < 64; off <<= 1) {
            float pA = __shfl_up(A, off, 64);
            float pB = __shfl_up(B, off, 64);
            if (lane >= off) { B = A * pB + B; A = A * pA; }
        }

        if (lane == 63) { wA[wave] = A; wB[wave] = B; }
        __syncthreads();

        float pA = 1.f, pB = 0.f;
#pragma unroll
        for (int w = 0; w < 3; ++w) {
            if (w < wave) {
                const float aw = wA[w], bw = wB[w];
                pB = aw * pB + bw;
                pA = aw * pA;
            }
        }
        const float iA = A * pA;
        const float iB = A * pB + B;
        sA[tid] = iA; sB[tid] = iB;
        __syncthreads();

        float gA = 1.f, gB = 0.f;
        if (tid != 0) { gA = sA[tid - 1]; gB = sB[tid - 1]; }
        float gamma = gA * carry + gB;

        const float cA = sA[THREADS - 1], cB = sB[THREADS - 1];
        carry = cA * carry + cB;

        float4* o = reinterpret_cast<float4*>(out + rbase + (long long)s * SEG_LEN + tid * PER);
#pragma unroll
        for (int j = 0; j < 2; ++j) {
            const float4 e = ev[j], d = dv[j];
            float4 sg;
            { float df = e.x - gamma; sg.x = E_INF_C * e.x + E_C * df; gamma += d.x * K_C * df; }
            { float df = e.y - gamma; sg.y = E_INF_C * e.y + E_C * df; gamma += d.y * K_C * df; }
            { float df = e.z - gamma; sg.z = E_INF_C * e.z + E_C * df; gamma += d.z * K_C * df; }
            { float df = e.w - gamma; sg.w = E_INF_C * e.w + E_C * df; gamma += d.w * K_C * df; }
            o[j] = sg;
        }

        if (s + 1 < SEGS) {
            ev[0] = evn[0]; ev[1] = evn[1];
            dv[0] = dvn[0]; dv[1] = dvn[1];
        }
    }
}

// ---- probe 1: m13-style flat grid-stride float4 read of both inputs ----
__global__ __launch_bounds__(256) void bw_probe_flat(
    const float4* __restrict__ a, const float4* __restrict__ b,
    long long n4, float* __restrict__ sink)
{
    long long i = (long long)blockIdx.x * blockDim.x + threadIdx.x;
    const long long stride = (long long)gridDim.x * blockDim.x;
    float acc = 0.f;
    for (; i < n4; i += stride) {
        const float4 x = a[i], y = b[i];
        acc += x.x + x.y + x.z + x.w + y.x + y.y + y.z + y.w;
    }
    if (acc == 1.2345e30f) sink[blockIdx.x] = acc;   // never true; keeps loads live
}

// ---- probe 2: v3-identical addressing (block-per-row, tid*PER, 4 segs) ----
__global__ __launch_bounds__(THREADS) void bw_probe_shaped(
    const float* __restrict__ eps, const float* __restrict__ dts,
    float* __restrict__ sink)
{
    const int row = blockIdx.x;
    const int tid = threadIdx.x;
    const long long rbase = (long long)row * T_LEN;
    float acc = 0.f;
#pragma unroll
    for (int s = 0; s < SEGS; ++s) {
        const long long nb = rbase + (long long)s * SEG_LEN + tid * PER;
        const float4* p = reinterpret_cast<const float4*>(eps + nb);
        const float4* q = reinterpret_cast<const float4*>(dts + nb);
        const float4 e0 = p[0], e1 = p[1], d0 = q[0], d1 = q[1];
        acc += e0.x + e0.y + e0.z + e0.w + e1.x + e1.y + e1.z + e1.w
             + d0.x + d0.y + d0.z + d0.w + d1.x + d1.y + d1.z + d1.w;
    }
    if (acc == 1.2345e30f) sink[row] = acc;          // never true
}

extern "C" void kernel_launch(void* const* d_in, const int* in_sizes, int n_in,
                              void* d_out, int out_size, void* d_ws, size_t ws_size,
                              hipStream_t stream) {
    const float* eps = (const float*)d_in[0];
    const float* dts = (const float*)d_in[1];
    float* out = (float*)d_out;
    const int total = in_sizes[0];          // B * T
    const int nrows = total / T_LEN;        // 2048

    // real kernel first (correct output, unpolluted timing)
    maxwell_seg_kernel<<<nrows, THREADS, 0, stream>>>(eps, dts, out);

    // diagnostics (read-only; never write in practice)
    float* sink = (float*)d_ws;
    const long long n4 = (long long)total / 4;
    bw_probe_flat<<<nrows, 256, 0, stream>>>(
        (const float4*)eps, (const float4*)dts, n4, sink);
    bw_probe_shaped<<<nrows, THREADS, 0, stream>>>(eps, dts, sink);
}

// Round 17
// 178.703 us; speedup vs baseline: 1.1845x; 1.1845x over previous
//
#include <hip/hip_runtime.h>

// Maxwell recurrence, v6b = v3 structure + NONTEMPORAL output stores.
//   gamma_{n+1} = (1-2*dt)*gamma + 2*dt*eps ;  sig = 2.5*eps - 2*gamma
// Rationale: harness restore/poison makes the per-replay working set exceed
// the 256MB L3; output stores evict restored input lines. nt stores bypass
// L3 so input reads hit L3 more often (FETCH_SIZE should drop).
// v6b: __builtin_nontemporal_store needs a native vector type, not HIP float4.

typedef float f32x4 __attribute__((ext_vector_type(4)));

constexpr int T_LEN   = 8192;
constexpr int THREADS = 256;
constexpr int SEGS    = 4;
constexpr int SEG_LEN = T_LEN / SEGS;       // 2048
constexpr int PER     = SEG_LEN / THREADS;  // 8 elems/thread/segment
constexpr float E_INF_C = 0.5f;
constexpr float E_C     = 2.0f;
constexpr float K_C     = 2.0f;             // E/ETA

__global__ __launch_bounds__(THREADS) void maxwell_seg_kernel(
    const float* __restrict__ eps, const float* __restrict__ dts,
    float* __restrict__ out)
{
    const int row  = blockIdx.x;
    const int tid  = threadIdx.x;
    const int lane = tid & 63;
    const int wave = tid >> 6;

    __shared__ float wA[4], wB[4];
    __shared__ float sA[THREADS], sB[THREADS];

    const long long rbase = (long long)row * T_LEN;

    float4 ev[2], dv[2], evn[2], dvn[2];
    {
        const float4* p = reinterpret_cast<const float4*>(eps + rbase + tid * PER);
        const float4* q = reinterpret_cast<const float4*>(dts + rbase + tid * PER);
        ev[0] = p[0]; ev[1] = p[1];
        dv[0] = q[0]; dv[1] = q[1];
    }

    float carry = 0.f;

#pragma unroll
    for (int s = 0; s < SEGS; ++s) {
        if (s + 1 < SEGS) {
            const long long nb = rbase + (long long)(s + 1) * SEG_LEN + tid * PER;
            const float4* p = reinterpret_cast<const float4*>(eps + nb);
            const float4* q = reinterpret_cast<const float4*>(dts + nb);
            evn[0] = p[0]; evn[1] = p[1];
            dvn[0] = q[0]; dvn[1] = q[1];
        }

        // local affine compose: g -> a*g + b
        float a = 1.f, b = 0.f;
#pragma unroll
        for (int j = 0; j < 2; ++j) {
            const float4 e = ev[j], d = dv[j];
            float an, t;
            t = K_C * d.x; an = 1.f - t; b = an * b + t * e.x; a = an * a;
            t = K_C * d.y; an = 1.f - t; b = an * b + t * e.y; a = an * a;
            t = K_C * d.z; an = 1.f - t; b = an * b + t * e.z; a = an * a;
            t = K_C * d.w; an = 1.f - t; b = an * b + t * e.w; a = an * a;
        }

        // wave inclusive scan
        float A = a, B = b;
#pragma unroll
        for (int off = 1; off < 64; off <<= 1) {
            float pA = __shfl_up(A, off, 64);
            float pB = __shfl_up(B, off, 64);
            if (lane >= off) { B = A * pB + B; A = A * pA; }
        }

        if (lane == 63) { wA[wave] = A; wB[wave] = B; }
        __syncthreads();

        // cross-wave prefix (4 waves)
        float pA = 1.f, pB = 0.f;
#pragma unroll
        for (int w = 0; w < 3; ++w) {
            if (w < wave) {
                const float aw = wA[w], bw = wB[w];
                pB = aw * pB + bw;
                pA = aw * pA;
            }
        }
        const float iA = A * pA;
        const float iB = A * pB + B;
        sA[tid] = iA; sB[tid] = iB;
        __syncthreads();

        float gA = 1.f, gB = 0.f;
        if (tid != 0) { gA = sA[tid - 1]; gB = sB[tid - 1]; }
        float gamma = gA * carry + gB;

        const float cA = sA[THREADS - 1], cB = sB[THREADS - 1];
        carry = cA * carry + cB;

        // replay + NONTEMPORAL store (native vector type for the builtin)
        f32x4* o = reinterpret_cast<f32x4*>(out + rbase + (long long)s * SEG_LEN + tid * PER);
#pragma unroll
        for (int j = 0; j < 2; ++j) {
            const float4 e = ev[j], d = dv[j];
            f32x4 sg;
            { float df = e.x - gamma; sg.x = E_INF_C * e.x + E_C * df; gamma += d.x * K_C * df; }
            { float df = e.y - gamma; sg.y = E_INF_C * e.y + E_C * df; gamma += d.y * K_C * df; }
            { float df = e.z - gamma; sg.z = E_INF_C * e.z + E_C * df; gamma += d.z * K_C * df; }
            { float df = e.w - gamma; sg.w = E_INF_C * e.w + E_C * df; gamma += d.w * K_C * df; }
            __builtin_nontemporal_store(sg, o + j);
        }

        if (s + 1 < SEGS) {
            ev[0] = evn[0]; ev[1] = evn[1];
            dv[0] = dvn[0]; dv[1] = dvn[1];
        }
    }
}

extern "C" void kernel_launch(void* const* d_in, const int* in_sizes, int n_in,
                              void* d_out, int out_size, void* d_ws, size_t ws_size,
                              hipStream_t stream) {
    const float* eps = (const float*)d_in[0];
    const float* dts = (const float*)d_in[1];
    float* out = (float*)d_out;
    const int total = in_sizes[0];          // B * T
    const int nrows = total / T_LEN;        // 2048
    maxwell_seg_kernel<<<nrows, THREADS, 0, stream>>>(eps, dts, out);
}